// Round 3
// baseline (334.046 us; speedup 1.0000x reference)
//
#include <hip/hip_runtime.h>
#include <hip/hip_cooperative_groups.h>
#include <math.h>

namespace cg = cooperative_groups;

// ---------------------------------------------------------------------------
// Single cooperative-kernel implementation.
// Reference semantics (JAX f32, x64 disabled): duplicate neighbor indices in
// the valid prefix of any row -> bitwise-identical S22 rows (1e-12 nugget
// vanishes in f32) -> exactly singular LU -> NaN weights -> NaN column avgs
// -> m = 0 -> mean_factors == 0, variances == 1.
// Phase 1 computes the dup flag from the inputs (deterministic, every call),
// dominant path writes zeros+ones; full f32 GEPP fallback pipeline kept
// in-kernel behind the uniform branch for the no-duplicate case.
// ws layout: [0..511] double colsq[64] | [512..1023] ll cnt[64]
// ---------------------------------------------------------------------------

#define MM 64

__global__ __launch_bounds__(64) void vecchia_coop_kernel(
    const int* __restrict__ batch_idx,
    const float* __restrict__ locs,
    const int* __restrict__ nn,
    const float* __restrict__ log_ls,
    float* __restrict__ out,        // [N*64 mean_factors | N variances]
    double* __restrict__ colsq,
    long long* __restrict__ cnt,
    int N, int G)
{
    cg::grid_group grid = cg::this_grid();
    const int lane = threadIdx.x;
    const int bid  = blockIdx.x;
    const long long total = (long long)N * MM;

    // ---- phase 1: per-block duplicate partial over its row share ----
    int part = 0;
    for (int row = bid; row < N; row += G) {
        const int ptr = batch_idx[row];
        const int nv  = ptr < MM ? ptr : MM;
        // unique sentinel for invalid lanes so they never collide
        int idx = (lane < nv) ? nn[(long long)ptr * MM + lane] : (-1 - lane);
        int dup = 0;
        // cyclic rotations s=1..32 cover every unordered lane pair
        #pragma unroll
        for (int s = 1; s <= 32; ++s) {
            int other = __shfl(idx, (lane + s) & (MM - 1));
            dup |= (other == idx) ? 1 : 0;
        }
        part |= (__ballot(dup) != 0ull) ? 1 : 0;
    }
    if (lane == 0) ((int*)out)[total + bid] = part;   // stash in variance region
    grid.sync();

    // ---- phase 2: grid-wide OR (every block computes the same value) ----
    int acc = 0;
    for (int i = lane; i < G; i += 64) acc |= ((const int*)out)[total + i];
    const bool anyDup = (__ballot(acc != 0) != 0ull);
    grid.sync();   // all partial reads done before out is overwritten

    if (anyDup) {
        // Dominant path: m = 0 -> zero mean_factors, unit variances.
        const long long tid    = (long long)bid * 64 + lane;
        const long long stride = (long long)G * 64;
        float4 z = make_float4(0.f, 0.f, 0.f, 0.f);
        float4* o4 = (float4*)out;
        const long long q = total >> 2;          // N*64 divisible by 4
        for (long long i = tid; i < q; i += stride) o4[i] = z;
        for (long long i = tid; i < N; i += stride) out[total + i] = 1.0f;
        return;   // uniform across the whole grid
    }

    // ======== fallback: faithful f32 pipeline (unreachable on bench data) ====
    __shared__ float A[MM][MM + 1];
    __shared__ float rhs[MM];
    __shared__ float px_s[MM];
    __shared__ float py_s[MM];

    const float ls = expf(log_ls[0]);
    const float SQRT5 = 2.23606797749978969f;

    for (int row = bid; row < N; row += G) {
        const int  ptr = batch_idx[row];
        const int  nv  = ptr < MM ? ptr : MM;
        const bool valid = lane < nv;

        const int   ci = nn[(long long)ptr * MM + lane];
        const float px = locs[2 * ci];
        const float py = locs[2 * ci + 1];
        const float cx = locs[2 * ptr];
        const float cy = locs[2 * ptr + 1];
        px_s[lane] = px;
        py_s[lane] = py;
        __syncthreads();

        for (int r = 0; r < MM; ++r) {
            float dx = px_s[r] - px;
            float dy = py_s[r] - py;
            float d2 = fmaxf(dx * dx + dy * dy, 1e-30f);
            float rr = sqrtf(d2) / ls;
            float K  = (1.0f + SQRT5 * rr + (5.0f / 3.0f) * rr * rr) * expf(-SQRT5 * rr);
            bool pv = valid && (r < nv);
            float e;
            if (r == lane) e = pv ? (K + 1e-12f) : 1.0f;
            else           e = pv ? K : 0.0f;
            A[r][lane] = e;
        }
        {
            float dx = cx - px;
            float dy = cy - py;
            float d2 = fmaxf(dx * dx + dy * dy, 1e-30f);
            float rr = sqrtf(d2) / ls;
            float K  = (1.0f + SQRT5 * rr + (5.0f / 3.0f) * rr * rr) * expf(-SQRT5 * rr);
            rhs[lane] = valid ? K : 0.0f;
        }
        __syncthreads();

        for (int k = 0; k < MM; ++k) {
            float v  = (lane >= k) ? fabsf(A[lane][k]) : -1.0f;
            int   id = lane;
            for (int off = 32; off > 0; off >>= 1) {
                float ov = __shfl_down(v, off);
                int   oi = __shfl_down(id, off);
                if (ov > v || (ov == v && oi < id)) { v = ov; id = oi; }
            }
            const int p = __shfl(id, 0);
            if (p != k) {
                float t = A[k][lane];
                A[k][lane] = A[p][lane];
                A[p][lane] = t;
                if (lane == 0) { float t2 = rhs[k]; rhs[k] = rhs[p]; rhs[p] = t2; }
            }
            __syncthreads();
            const float piv = A[k][k];
            if (lane > k) {
                const float mlt = A[lane][k] / piv;
                #pragma unroll 4
                for (int j = k + 1; j < MM; ++j)
                    A[lane][j] -= mlt * A[k][j];
                rhs[lane] -= mlt * rhs[k];
            }
            __syncthreads();
        }

        float w = 0.0f;
        for (int k = MM - 1; k >= 0; --k) {
            const float xk = rhs[k] / A[k][k];
            if (lane == k) w = xk;
            if (lane < k)  rhs[lane] -= A[lane][k] * xk;
            __syncthreads();
        }
        w = valid ? w : 0.0f;
        out[(long long)row * MM + lane] = w;
        __syncthreads();
    }
    grid.sync();

    // colred: block j (j<64) owns column j; deterministic fixed-order sums
    if (bid < MM) {
        const int j = bid;
        double s = 0.0;
        long long c = 0;
        for (int i = lane; i < N; i += 64) {
            double w = (double)out[(long long)i * MM + j];
            s += w * w;
            c += (batch_idx[i] > j) ? 1 : 0;
        }
        // fixed-order tree reduce across the wave
        for (int off = 32; off > 0; off >>= 1) {
            s += __shfl_down(s, off);
            long long oc = __shfl_down(c, off);
            c += oc;
        }
        if (lane == 0) { colsq[j] = s; cnt[j] = c; }
    }
    grid.sync();

    // cutoff: every block computes the same m
    {
        double avg = colsq[lane] / (double)cnt[lane];
        int pass = (avg >= 1e-4) ? 1 : 0;             // NaN -> false
        unsigned long long b = __ballot(pass);
        const int m = (int)__popcll(b);

        const long long tid    = (long long)bid * 64 + lane;
        const long long stride = (long long)G * 64;
        for (long long idx = tid; idx < total; idx += stride) {
            int j = (int)(idx & (MM - 1));
            if (j >= m) out[idx] = 0.0f;
        }
        for (long long i = tid; i < N; i += stride) out[total + i] = 1.0f;
    }
}

extern "C" void kernel_launch(void* const* d_in, const int* in_sizes, int n_in,
                              void* d_out, int out_size, void* d_ws, size_t ws_size,
                              hipStream_t stream) {
    const int*   batch_idx = (const int*)d_in[0];
    const float* locs      = (const float*)d_in[1];
    const int*   nn        = (const int*)d_in[2];
    const float* log_ls    = (const float*)d_in[3];
    int N = in_sizes[0];

    float*     out   = (float*)d_out;
    double*    colsq = (double*)d_ws;
    long long* cnt   = (long long*)((char*)d_ws + 512);

    int occ = 0;
    hipError_t e = hipOccupancyMaxActiveBlocksPerMultiprocessor(
        &occ, vecchia_coop_kernel, 64, 0);
    if (e != hipSuccess || occ < 1) occ = 2;   // conservative fallback
    if (occ > 8) occ = 8;
    int G = occ * 256;                          // MI355X: 256 CUs
    if (G > 2048) G = 2048;
    if (G < 64)   G = 64;                       // colred needs 64 blocks

    void* args[] = { (void*)&batch_idx, (void*)&locs, (void*)&nn, (void*)&log_ls,
                     (void*)&out, (void*)&colsq, (void*)&cnt, (void*)&N, (void*)&G };
    hipLaunchCooperativeKernel(vecchia_coop_kernel, dim3(G), dim3(64),
                               args, 0, stream);
}

// Round 4
// 33.975 us; speedup vs baseline: 9.8322x; 9.8322x over previous
//
#include <hip/hip_runtime.h>
#include <math.h>

// ---------------------------------------------------------------------------
// Reference semantics (JAX f32): duplicate neighbor indices within a row's
// valid prefix -> bitwise-identical S22 rows (1e-12 nugget vanishes in f32)
// -> singular LU -> NaN weights -> NaN column averages -> m = 0 ->
// mean_factors == 0, variances == 1.
// Chain: dup partials (no memset needed) -> solve (early-exit) ->
// colred (early-exit) -> finalize (flag + m computed in-wave).
// ws: [0,1024) int partial[256] | [1024,1536) double colsq[64]
//     | [1536,2048) ll cnt[64]
// ---------------------------------------------------------------------------

#define MM 64
#define NPART 256

__global__ __launch_bounds__(256) void dup_partial_kernel(
    const int* __restrict__ batch_idx,
    const int* __restrict__ nn,
    int* __restrict__ partial, int N)
{
    const int wave = threadIdx.x >> 6;
    const int lane = threadIdx.x & 63;
    int any = 0;
    for (int row = blockIdx.x * 4 + wave; row < N; row += NPART * 4) {
        const int ptr = batch_idx[row];
        const int nv  = ptr < MM ? ptr : MM;
        // unique sentinel for invalid lanes so they never collide
        int idx = (lane < nv) ? nn[(long long)ptr * MM + lane] : (-1 - lane);
        int dup = 0;
        // cyclic rotations s=1..32 cover every unordered lane pair
        #pragma unroll
        for (int s = 1; s <= 32; ++s) {
            int other = __shfl(idx, (lane + s) & (MM - 1));
            dup |= (other == idx) ? 1 : 0;
        }
        any |= (__ballot(dup) != 0ull) ? 1 : 0;
    }
    __shared__ int sw[4];
    if (lane == 0) sw[wave] = any;
    __syncthreads();
    if (threadIdx.x == 0)
        partial[blockIdx.x] = sw[0] | sw[1] | sw[2] | sw[3];
}

__device__ __forceinline__ bool wave_flag(const int* __restrict__ partial) {
    const int lane = threadIdx.x & 63;
    int acc = 0;
    #pragma unroll
    for (int i = 0; i < NPART / 64; ++i) acc |= partial[lane + i * 64];
    return __ballot(acc != 0) != 0ull;
}

// Fallback f32 GEPP solve (early-exits on the bench data).
__global__ __launch_bounds__(64) void solve_kernel(
    const int* __restrict__ partial,
    const int* __restrict__ batch_idx,
    const float* __restrict__ locs,
    const int* __restrict__ nn,
    const float* __restrict__ log_ls,
    float* __restrict__ out_mean,
    int N)
{
    if (wave_flag(partial)) return;

    __shared__ float A[MM][MM + 1];
    __shared__ float rhs[MM];
    __shared__ float px_s[MM];
    __shared__ float py_s[MM];

    const int lane = threadIdx.x;
    const float ls = expf(log_ls[0]);
    const float SQRT5 = 2.23606797749978969f;

    for (int row = blockIdx.x; row < N; row += gridDim.x) {
        const int  ptr = batch_idx[row];
        const int  nv  = ptr < MM ? ptr : MM;
        const bool valid = lane < nv;

        const int   ci = nn[(long long)ptr * MM + lane];
        const float px = locs[2 * ci];
        const float py = locs[2 * ci + 1];
        const float cx = locs[2 * ptr];
        const float cy = locs[2 * ptr + 1];
        px_s[lane] = px;
        py_s[lane] = py;
        __syncthreads();

        for (int r = 0; r < MM; ++r) {
            float dx = px_s[r] - px;
            float dy = py_s[r] - py;
            float d2 = fmaxf(dx * dx + dy * dy, 1e-30f);
            float rr = sqrtf(d2) / ls;
            float K  = (1.0f + SQRT5 * rr + (5.0f / 3.0f) * rr * rr) * expf(-SQRT5 * rr);
            bool pv = valid && (r < nv);
            float e;
            if (r == lane) e = pv ? (K + 1e-12f) : 1.0f;
            else           e = pv ? K : 0.0f;
            A[r][lane] = e;
        }
        {
            float dx = cx - px;
            float dy = cy - py;
            float d2 = fmaxf(dx * dx + dy * dy, 1e-30f);
            float rr = sqrtf(d2) / ls;
            float K  = (1.0f + SQRT5 * rr + (5.0f / 3.0f) * rr * rr) * expf(-SQRT5 * rr);
            rhs[lane] = valid ? K : 0.0f;
        }
        __syncthreads();

        for (int k = 0; k < MM; ++k) {
            float v  = (lane >= k) ? fabsf(A[lane][k]) : -1.0f;
            int   id = lane;
            for (int off = 32; off > 0; off >>= 1) {
                float ov = __shfl_down(v, off);
                int   oi = __shfl_down(id, off);
                if (ov > v || (ov == v && oi < id)) { v = ov; id = oi; }
            }
            const int p = __shfl(id, 0);
            if (p != k) {
                float t = A[k][lane];
                A[k][lane] = A[p][lane];
                A[p][lane] = t;
                if (lane == 0) { float t2 = rhs[k]; rhs[k] = rhs[p]; rhs[p] = t2; }
            }
            __syncthreads();
            const float piv = A[k][k];
            if (lane > k) {
                const float mlt = A[lane][k] / piv;
                #pragma unroll 4
                for (int j = k + 1; j < MM; ++j)
                    A[lane][j] -= mlt * A[k][j];
                rhs[lane] -= mlt * rhs[k];
            }
            __syncthreads();
        }

        float w = 0.0f;
        for (int k = MM - 1; k >= 0; --k) {
            const float xk = rhs[k] / A[k][k];
            if (lane == k) w = xk;
            if (lane < k)  rhs[lane] -= A[lane][k] * xk;
            __syncthreads();
        }
        w = valid ? w : 0.0f;
        out_mean[(long long)row * MM + lane] = w;
        __syncthreads();
    }
}

__global__ __launch_bounds__(256) void colred_kernel(
    const int* __restrict__ partial,
    const float* __restrict__ mean,
    const int* __restrict__ batch_idx,
    double* __restrict__ colsq,
    long long* __restrict__ cnt,
    int N)
{
    if (wave_flag(partial)) return;
    const int j = blockIdx.x;
    const int t = threadIdx.x;
    double s = 0.0;
    long long c = 0;
    for (int i = t; i < N; i += 256) {
        double w = (double)mean[(long long)i * MM + j];
        s += w * w;
        c += (batch_idx[i] > j) ? 1 : 0;
    }
    __shared__ double    sd[256];
    __shared__ long long sc[256];
    sd[t] = s; sc[t] = c;
    __syncthreads();
    for (int off = 128; off > 0; off >>= 1) {
        if (t < off) { sd[t] += sd[t + off]; sc[t] += sc[t + off]; }
        __syncthreads();
    }
    if (t == 0) { colsq[j] = sd[0]; cnt[j] = sc[0]; }
}

__global__ __launch_bounds__(256) void finalize_kernel(
    const int* __restrict__ partial,
    const double* __restrict__ colsq,
    const long long* __restrict__ cnt,
    float* __restrict__ out,
    int N)
{
    const bool anyDup = wave_flag(partial);
    const long long total  = (long long)N * MM;
    const long long tid    = (long long)blockIdx.x * 256 + threadIdx.x;
    const long long stride = (long long)gridDim.x * 256;

    int m = 0;
    if (!anyDup) {
        const int j = threadIdx.x & 63;
        double avg = colsq[j] / (double)cnt[j];
        int pass = (avg >= 1e-4) ? 1 : 0;            // NaN -> false
        m = (int)__popcll(__ballot(pass));
    }

    if (m == 0) {
        float4 z = make_float4(0.f, 0.f, 0.f, 0.f);
        float4* o4 = (float4*)out;
        const long long q = total >> 2;               // N*64 % 4 == 0
        for (long long i = tid; i < q; i += stride) o4[i] = z;
        float4 one = make_float4(1.f, 1.f, 1.f, 1.f);
        float4* v4 = (float4*)(out + total);
        const long long qv = (long long)N >> 2;       // N % 4 == 0
        for (long long i = tid; i < qv; i += stride) v4[i] = one;
        for (long long i = (qv << 2) + tid; i < N; i += stride) out[total + i] = 1.0f;
    } else {
        for (long long idx = tid; idx < total; idx += stride) {
            int j = (int)(idx & (MM - 1));
            if (j >= m) out[idx] = 0.0f;
        }
        for (long long i = tid; i < N; i += stride) out[total + i] = 1.0f;
    }
}

extern "C" void kernel_launch(void* const* d_in, const int* in_sizes, int n_in,
                              void* d_out, int out_size, void* d_ws, size_t ws_size,
                              hipStream_t stream) {
    const int*   batch_idx = (const int*)d_in[0];
    const float* locs      = (const float*)d_in[1];
    const int*   nn        = (const int*)d_in[2];
    const float* log_ls    = (const float*)d_in[3];
    const int N = in_sizes[0];

    float*     out     = (float*)d_out;
    int*       partial = (int*)d_ws;
    double*    colsq   = (double*)((char*)d_ws + 1024);
    long long* cnt     = (long long*)((char*)d_ws + 1536);

    dup_partial_kernel<<<NPART, 256, 0, stream>>>(batch_idx, nn, partial, N);
    solve_kernel<<<2048, 64, 0, stream>>>(partial, batch_idx, locs, nn, log_ls, out, N);
    colred_kernel<<<64, 256, 0, stream>>>(partial, out, batch_idx, colsq, cnt, N);
    finalize_kernel<<<1024, 256, 0, stream>>>(partial, colsq, cnt, out, N);
}

// Round 5
// 22.478 us; speedup vs baseline: 14.8612x; 1.5115x over previous
//
#include <hip/hip_runtime.h>
#include <math.h>

// ---------------------------------------------------------------------------
// Reference semantics (JAX f32): duplicate neighbor indices within a row's
// valid prefix -> bitwise-identical S22 rows (1e-12 nugget vanishes in f32)
// -> singular LU -> NaN weights -> NaN column averages -> m = 0 ->
// mean_factors == 0, variances == 1.
// Two dispatches:
//   K1 prep : dup partials (recomputed from inputs every call, no memset),
//             variances = 1 (always true), barrier-counter reset.
//   K2 final: hot path (any dup) -> zero mean_factors. No-dup fallback runs
//             the full f32 GEPP pipeline in-kernel with a hand-rolled grid
//             barrier (co-residency: 21.5KB LDS -> 7 blocks/CU * 256 CUs
//             = 1792 >= 1024 launched blocks).
// ws: [0,2048) int partial[512] | [2048] int barcnt |
//     [2560,3072) double colsq[64] | [3072,3584) ll cnt[64]
// ---------------------------------------------------------------------------

#define MM 64
#define NPART 512
#define G2 1024

__global__ __launch_bounds__(256) void prep_kernel(
    const int* __restrict__ batch_idx,
    const int* __restrict__ nn,
    int* __restrict__ partial,
    int* __restrict__ barcnt,
    float* __restrict__ out,
    int N)
{
    if (blockIdx.x == 0 && threadIdx.x == 0) *barcnt = 0;

    const int wave = threadIdx.x >> 6;
    const int lane = threadIdx.x & 63;
    int any = 0;
    for (int row = blockIdx.x * 4 + wave; row < N; row += NPART * 4) {
        const int ptr = batch_idx[row];
        const int nv  = ptr < MM ? ptr : MM;
        // unique sentinel for invalid lanes so they never collide
        int idx = (lane < nv) ? nn[(long long)ptr * MM + lane] : (-1 - lane);
        int dup = 0;
        // cyclic rotations s=1..32 cover every unordered lane pair
        #pragma unroll
        for (int s = 1; s <= 32; ++s) {
            int other = __shfl(idx, (lane + s) & (MM - 1));
            dup |= (other == idx) ? 1 : 0;
        }
        any |= (__ballot(dup) != 0ull) ? 1 : 0;
    }
    __shared__ int sw[4];
    if (lane == 0) sw[wave] = any;
    __syncthreads();
    if (threadIdx.x == 0)
        partial[blockIdx.x] = sw[0] | sw[1] | sw[2] | sw[3];

    // variances = 1 unconditionally (true on every path)
    const long long total = (long long)N * MM;
    float4* v4 = (float4*)(out + total);
    const int qv = N >> 2;
    const float4 one = make_float4(1.f, 1.f, 1.f, 1.f);
    for (int i = blockIdx.x * 256 + threadIdx.x; i < qv; i += NPART * 256)
        v4[i] = one;
    for (int i = (qv << 2) + blockIdx.x * 256 + threadIdx.x; i < N; i += NPART * 256)
        out[total + i] = 1.0f;
}

__device__ __forceinline__ bool wave_flag(const int* __restrict__ partial) {
    const int lane = threadIdx.x & 63;
    int acc = 0;
    #pragma unroll
    for (int i = 0; i < NPART / 64; ++i) acc |= partial[lane + i * 64];
    return __ballot(acc != 0) != 0ull;
}

__device__ __forceinline__ void grid_bar(int* barcnt, int target) {
    __syncthreads();
    if (threadIdx.x == 0) {
        __threadfence();
        atomicAdd(barcnt, 1);
        while (atomicAdd(barcnt, 0) < target) {}
        __threadfence();
    }
    __syncthreads();
}

__global__ __launch_bounds__(256) void final_kernel(
    const int* __restrict__ partial,
    const int* __restrict__ batch_idx,
    const float* __restrict__ locs,
    const int* __restrict__ nn,
    const float* __restrict__ log_ls,
    float* __restrict__ out,
    int* __restrict__ barcnt,
    double* __restrict__ colsq,
    long long* __restrict__ cnt,
    int N)
{
    const bool anyDup = wave_flag(partial);
    const long long total  = (long long)N * MM;
    const long long tid    = (long long)blockIdx.x * 256 + threadIdx.x;
    const long long stride = (long long)G2 * 256;

    if (anyDup) {
        // Dominant path: m = 0 -> zero mean_factors (variances done in K1).
        const float4 z = make_float4(0.f, 0.f, 0.f, 0.f);
        float4* o4 = (float4*)out;
        const long long q = total >> 2;          // N*64 % 4 == 0
        for (long long i = tid; i < q; i += stride) o4[i] = z;
        return;                                   // uniform across grid
    }

    // ===== fallback: faithful f32 pipeline (unreachable on bench data) =====
    __shared__ float A[MM][MM + 1];
    __shared__ float rhs[MM];
    __shared__ float px_s[MM];
    __shared__ float py_s[MM];

    const int lane = threadIdx.x & 63;
    const int wv   = threadIdx.x >> 6;
    const float ls = expf(log_ls[0]);
    const float SQRT5 = 2.23606797749978969f;

    // phase 1: GEPP solve, one row per block iteration (wave 0 computes)
    for (int row = blockIdx.x; row < N; row += G2) {
        const int  ptr = batch_idx[row];
        const int  nv  = ptr < MM ? ptr : MM;
        const bool valid = lane < nv;

        float px = 0.f, py = 0.f, cx = 0.f, cy = 0.f;
        if (wv == 0) {
            const int ci = nn[(long long)ptr * MM + lane];
            px = locs[2 * ci];  py = locs[2 * ci + 1];
            cx = locs[2 * ptr]; cy = locs[2 * ptr + 1];
            px_s[lane] = px;    py_s[lane] = py;
        }
        __syncthreads();
        if (wv == 0) {
            for (int r = 0; r < MM; ++r) {
                float dx = px_s[r] - px, dy = py_s[r] - py;
                float d2 = fmaxf(dx * dx + dy * dy, 1e-30f);
                float rr = sqrtf(d2) / ls;
                float K  = (1.f + SQRT5 * rr + (5.f / 3.f) * rr * rr) * expf(-SQRT5 * rr);
                bool pv = valid && (r < nv);
                A[r][lane] = (r == lane) ? (pv ? K + 1e-12f : 1.f) : (pv ? K : 0.f);
            }
            float dx = cx - px, dy = cy - py;
            float d2 = fmaxf(dx * dx + dy * dy, 1e-30f);
            float rr = sqrtf(d2) / ls;
            float K  = (1.f + SQRT5 * rr + (5.f / 3.f) * rr * rr) * expf(-SQRT5 * rr);
            rhs[lane] = valid ? K : 0.f;
        }
        __syncthreads();

        for (int k = 0; k < MM; ++k) {
            if (wv == 0) {
                float v  = (lane >= k) ? fabsf(A[lane][k]) : -1.f;
                int   id = lane;
                for (int off = 32; off > 0; off >>= 1) {
                    float ov = __shfl_down(v, off);
                    int   oi = __shfl_down(id, off);
                    if (ov > v || (ov == v && oi < id)) { v = ov; id = oi; }
                }
                const int p = __shfl(id, 0);
                if (p != k) {
                    float t = A[k][lane];
                    A[k][lane] = A[p][lane];
                    A[p][lane] = t;
                    if (lane == 0) { float t2 = rhs[k]; rhs[k] = rhs[p]; rhs[p] = t2; }
                }
            }
            __syncthreads();
            if (wv == 0 && lane > k) {
                const float piv = A[k][k];
                const float mlt = A[lane][k] / piv;
                #pragma unroll 4
                for (int j = k + 1; j < MM; ++j)
                    A[lane][j] -= mlt * A[k][j];
                rhs[lane] -= mlt * rhs[k];
            }
            __syncthreads();
        }

        float w = 0.f;
        for (int k = MM - 1; k >= 0; --k) {
            if (wv == 0) {
                const float xk = rhs[k] / A[k][k];
                if (lane == k) w = xk;
                if (lane < k)  rhs[lane] -= A[lane][k] * xk;
            }
            __syncthreads();
        }
        if (wv == 0) out[(long long)row * MM + lane] = valid ? w : 0.f;
        __syncthreads();
    }
    grid_bar(barcnt, G2);

    // phase 2: per-column reduction (blocks 0..63, deterministic order)
    if (blockIdx.x < MM) {
        const int j = blockIdx.x;
        const int t = threadIdx.x;
        double s = 0.0;
        long long c = 0;
        for (int i = t; i < N; i += 256) {
            double w = (double)out[(long long)i * MM + j];
            s += w * w;
            c += (batch_idx[i] > j) ? 1 : 0;
        }
        __shared__ double    sd[256];
        __shared__ long long sc[256];
        sd[t] = s; sc[t] = c;
        __syncthreads();
        for (int off = 128; off > 0; off >>= 1) {
            if (t < off) { sd[t] += sd[t + off]; sc[t] += sc[t + off]; }
            __syncthreads();
        }
        if (t == 0) { colsq[j] = sd[0]; cnt[j] = sc[0]; }
    }
    grid_bar(barcnt, 2 * G2);

    // phase 3: cutoff + zero trailing columns (every wave computes same m)
    {
        double avg = colsq[lane] / (double)cnt[lane];
        int pass = (avg >= 1e-4) ? 1 : 0;            // NaN -> false
        const int m = (int)__popcll(__ballot(pass));
        for (long long idx = tid; idx < total; idx += stride) {
            int j = (int)(idx & (MM - 1));
            if (j >= m) out[idx] = 0.0f;
        }
    }
}

extern "C" void kernel_launch(void* const* d_in, const int* in_sizes, int n_in,
                              void* d_out, int out_size, void* d_ws, size_t ws_size,
                              hipStream_t stream) {
    const int*   batch_idx = (const int*)d_in[0];
    const float* locs      = (const float*)d_in[1];
    const int*   nn        = (const int*)d_in[2];
    const float* log_ls    = (const float*)d_in[3];
    const int N = in_sizes[0];

    float*     out     = (float*)d_out;
    int*       partial = (int*)d_ws;
    int*       barcnt  = (int*)((char*)d_ws + 2048);
    double*    colsq   = (double*)((char*)d_ws + 2560);
    long long* cnt     = (long long*)((char*)d_ws + 3072);

    prep_kernel<<<NPART, 256, 0, stream>>>(batch_idx, nn, partial, barcnt, out, N);
    final_kernel<<<G2, 256, 0, stream>>>(partial, batch_idx, locs, nn, log_ls,
                                         out, barcnt, colsq, cnt, N);
}